// Round 22
// baseline (57.532 us; speedup 1.0000x reference)
//
#include <hip/hip_runtime.h>
#include <hip/hip_bf16.h>

#define LSEQ 2048
#define BB   2048
#define TT   7
#define NFLD 17   // SoA fields: [0..6] vn, [7..13] rn, [14] sc, [15] mc, [16] Lmass

typedef float f4 __attribute__((ext_vector_type(4)));

// Load 7 floats from a 4B-aligned row as two overlapping dwordx4 loads.
__device__ __forceinline__ void ld7(const float* __restrict__ p, float* e) {
  f4 lo, hi;
  __builtin_memcpy(&lo, p, 16);
  __builtin_memcpy(&hi, p + 3, 16);
  e[0] = lo.x; e[1] = lo.y; e[2] = lo.z; e[3] = lo.w;
  e[4] = hi.y; e[5] = hi.z; e[6] = hi.w;
}

// ---------------------------------------------------------------------------
// Rank-1 chunk decomposition, v10 = R21 structure at KCH=128.
// P_c = u s v^T, s = 1^T P 1.
//   forward (CC=16 steps, 1 chunk/thread): v <- (v.E) o ee -> vn, Lmass,
//     gold sc, mask count.
//   backward (NB=8 steps, 1 chunk/thread): u DIRECTION only (~1e-8).
// MODEL (validated R20->R21): time = bytes / BW(total_waves); BW follows
// Little's law in waves/CU (16/CU -> 2.4 TB/s). KCH=128 at S=1 doubles both
// role grids -> 8192 waves = 32/CU (HW max) at ~same HBM bytes (backward
// re-reads are L3-hot; records 17.8 MB). R16's KCH=128 failure was S=2
// (half waves) + NB=12 (75% re-read) — different config.
// Falsified (do not retry): LDS em tiles (R11/R18), branch-free loops (R19),
// asm rings (R14 fault), min-wave launch_bounds (R5/R7 spill).
// ---------------------------------------------------------------------------
template<int KCH>
__global__ __launch_bounds__(256)
void crf_chunk_kernel(const float* __restrict__ em,
                      const int*   __restrict__ tags,
                      const int*   __restrict__ qmask,
                      const int*   __restrict__ mask,
                      const float* __restrict__ self_t,
                      const float* __restrict__ other_t,
                      float* __restrict__ recs) {
  constexpr int CC   = LSEQ / KCH;
  constexpr int NG   = KCH * BB;
  constexpr int NB   = (CC < 8) ? CC : 8;   // backward steps for u direction
  constexpr int NFWD = NG / 256;            // forward blocks
  __shared__ float sE[2][49];        // exp(transitions): [0]=self, [1]=other
  __shared__ float sT[2][49];        // raw transitions (gold-path score)
  int tid = threadIdx.x;
  if (tid < 49) {
    float sv = self_t[tid], ov = other_t[tid];
    sE[0][tid] = __expf(sv); sE[1][tid] = __expf(ov);
    sT[0][tid] = sv;         sT[1][tid] = ov;
  }
  __syncthreads();

  float Es[49];                      // SGPR-resident via readfirstlane
  int loadedCont = -1;
  auto loadEs = [&](int cf) {
#pragma unroll
    for (int k = 0; k < 49; ++k)
      Es[k] = __int_as_float(
          __builtin_amdgcn_readfirstlane(__float_as_int(sE[cf][k])));
    loadedCont = cf;
  };

  int bid = blockIdx.x;
  if (bid < NFWD) {
    // ============ forward: vn, Lmass, gold score (1 chunk/thread) =========
    int g = bid * 256 + tid;
    int b = g & (BB - 1);
    int c = g >> 11;                 // uniform per block (256 | 2048)
    float v[7] = {1.f,1.f,1.f,1.f,1.f,1.f,1.f};
    float sc = 0.f, Lv = 0.f;
    int mc = 0, tp, qp;
    int i0 = c * CC;
    if (c == 0) { mc = mask[b]; tp = tags[b]; qp = qmask[b]; }
    else { size_t pb = (size_t)(i0 - 1) * BB + b; tp = tags[pb]; qp = qmask[pb]; }

    auto LDF = [&](int s, float* e, int& tg, int& qm, int& mi) {
      size_t base = (size_t)(i0 + s) * BB + b;
      ld7(em + base * TT, e);
      tg = tags[base]; qm = qmask[base]; mi = mask[base];
    };

    float e0[7], e1[7];
    int tg0, qm0, mi0, tg1, qm1, mi1;
    LDF(0, e0, tg0, qm0, mi0);

    for (int j = 0; j < CC; ++j) {
      bool more = (j + 1 < CC);                   // wave-uniform
      if (more) LDF(j + 1, e1, tg1, qm1, mi1);    // issue next-step loads

      int mi = (c == 0 && j == 0) ? 0 : mi0;      // boundary step = identity
      int cont = (qm0 != qp) ? 1 : 0;
      int cf = __builtin_amdgcn_readfirstlane(cont);
      bool uni = __all(cont == cf);
      float ee[7];
#pragma unroll
      for (int t = 0; t < 7; ++t) ee[t] = __expf(e0[t]);
      float etag = e0[0];
#pragma unroll
      for (int t = 1; t < 7; ++t) etag = (tg0 == t) ? e0[t] : etag;
      float ttag = sT[cont][tp * 7 + tg0];
      if (mi) { sc += ttag + etag; ++mc; }
      tp = tg0; qp = qm0;

      float a[7] = {0.f,0.f,0.f,0.f,0.f,0.f,0.f};
      if (uni) {
        if (cf != loadedCont) loadEs(cf);
#pragma unroll
        for (int r = 0; r < 7; ++r) {
          float vr = v[r];
#pragma unroll
          for (int t = 0; t < 7; ++t) a[t] = fmaf(vr, Es[r*7+t], a[t]);
        }
      } else {
        loadedCont = -1;
#pragma unroll
        for (int r = 0; r < 7; ++r) {
          float vr = v[r];
#pragma unroll
          for (int t = 0; t < 7; ++t) a[t] = fmaf(vr, sE[cont][r*7+t], a[t]);
        }
      }
#pragma unroll
      for (int t = 0; t < 7; ++t) v[t] = mi ? a[t] * ee[t] : v[t];

      if ((j & 7) == 7) {                         // renorm, track log mass
        float ss = v[0]+v[1]+v[2]+v[3]+v[4]+v[5]+v[6];
        Lv += logf(ss);
        float inv = 1.0f / ss;
#pragma unroll
        for (int t = 0; t < 7; ++t) v[t] *= inv;
      }
      if (more) {
#pragma unroll
        for (int t = 0; t < 7; ++t) e0[t] = e1[t];
        tg0 = tg1; qm0 = qm1; mi0 = mi1;
      }
    }
    float ss = v[0]+v[1]+v[2]+v[3]+v[4]+v[5]+v[6];
    float inv = 1.0f / ss;
#pragma unroll
    for (int t = 0; t < 7; ++t) recs[(size_t)t * NG + g] = v[t] * inv;
    recs[(size_t)14 * NG + g] = sc;
    recs[(size_t)15 * NG + g] = (float)mc;
    recs[(size_t)16 * NG + g] = Lv + logf(ss);    // Lmass = log(1^T P 1)
  } else {
    // ============ backward: u direction, NB steps (1 chunk/thread) ========
    int g = (bid - NFWD) * 256 + tid;
    int b = g & (BB - 1);
    int c = g >> 11;
    float r[7] = {1.f,1.f,1.f,1.f,1.f,1.f,1.f};
    int ilo = (c == 0) ? 1 : c * CC;

    auto LDB = [&](int s, float* e, int& q, int& q1, int& mi2) {
      size_t base = (size_t)(ilo + NB - 1 - s) * BB + b;    // i >= 1
      ld7(em + base * TT, e);
      q = qmask[base]; q1 = qmask[base - BB]; mi2 = mask[base];
    };

    float e0[7], e1[7];
    int q0, q10, m0, q1v, q11, m1;
    LDB(0, e0, q0, q10, m0);

    for (int j = 0; j < NB; ++j) {
      bool more = (j + 1 < NB);
      if (more) LDB(j + 1, e1, q1v, q11, m1);

      int cont = (q0 != q10) ? 1 : 0;
      int cf = __builtin_amdgcn_readfirstlane(cont);
      bool uni = __all(cont == cf);
      float ee[7];
#pragma unroll
      for (int t = 0; t < 7; ++t) ee[t] = __expf(e0[t]);
      float tmp[7];
#pragma unroll
      for (int t = 0; t < 7; ++t) tmp[t] = ee[t] * r[t];
      float a[7] = {0.f,0.f,0.f,0.f,0.f,0.f,0.f};
      if (uni) {
        if (cf != loadedCont) loadEs(cf);
#pragma unroll
        for (int t = 0; t < 7; ++t) {
          float tt = tmp[t];
#pragma unroll
          for (int s2 = 0; s2 < 7; ++s2) a[s2] = fmaf(tt, Es[s2*7+t], a[s2]);
        }
      } else {
        loadedCont = -1;
#pragma unroll
        for (int t = 0; t < 7; ++t) {
          float tt = tmp[t];
#pragma unroll
          for (int s2 = 0; s2 < 7; ++s2) a[s2] = fmaf(tt, sE[cont][s2*7+t], a[s2]);
        }
      }
#pragma unroll
      for (int s2 = 0; s2 < 7; ++s2) r[s2] = m0 ? a[s2] : r[s2];

      if (j == 3) {                               // overflow guard (mid-pass)
        float ss = r[0]+r[1]+r[2]+r[3]+r[4]+r[5]+r[6];
        float inv = 1.0f / ss;
#pragma unroll
        for (int t = 0; t < 7; ++t) r[t] *= inv;
      }
      if (more) {
#pragma unroll
        for (int t = 0; t < 7; ++t) e0[t] = e1[t];
        q0 = q1v; q10 = q11; m0 = m1;
      }
    }
    float ss = r[0]+r[1]+r[2]+r[3]+r[4]+r[5]+r[6];
    float inv = 1.0f / ss;
#pragma unroll
    for (int t = 0; t < 7; ++t) recs[(size_t)(7 + t) * NG + g] = r[t] * inv;
  }
}

// ---------------------------------------------------------------------------
// Kernel 2: flat-parallel junction terms + per-block tree reduction.
// term(b,c) = sc - Lmass - log(dot); dot_0 = alpha0.rn_0 (+gold start terms),
// dot_c = vn_{c-1}.rn_c; c==KCH-1 folds the final logZ term and gold end.
// ---------------------------------------------------------------------------
template<int KCH>
__global__ __launch_bounds__(256)
void crf_junction_kernel(const float* __restrict__ recs,
                         const float* __restrict__ em,
                         const int*   __restrict__ tags,
                         const float* __restrict__ start_t,
                         const float* __restrict__ end_t,
                         float* __restrict__ partials) {
  constexpr int NG = KCH * BB;
  int tid = threadIdx.x;
  int g = blockIdx.x * 256 + tid;
  int b = g & (BB - 1);
  int c = g >> 11;                       // block-uniform (256 | 2048)
  float rn[7];
#pragma unroll
  for (int t = 0; t < 7; ++t) rn[t] = recs[(size_t)(7 + t) * NG + g];
  float term = recs[(size_t)14 * NG + g] - recs[(size_t)16 * NG + g];
  float dot = 0.f;
  if (c == 0) {
    float e0[7], st[7];
#pragma unroll
    for (int t = 0; t < 7; ++t) { e0[t] = em[(size_t)b * TT + t]; st[t] = start_t[t]; }
#pragma unroll
    for (int t = 0; t < 7; ++t) dot = fmaf(__expf(st[t] + e0[t]), rn[t], dot);
    int tg0 = tags[b];
    float em0t = e0[0], stt = st[0];
#pragma unroll
    for (int t = 1; t < 7; ++t) {
      em0t = (tg0 == t) ? e0[t] : em0t;
      stt  = (tg0 == t) ? st[t] : stt;
    }
    term += stt + em0t;                  // gold start + em[0][tag0]
  } else {
#pragma unroll
    for (int t = 0; t < 7; ++t)
      dot = fmaf(recs[(size_t)t * NG + (g - BB)], rn[t], dot);
  }
  term -= logf(dot);
  if (c == KCH - 1) {
    float fz = 0.f;
#pragma unroll
    for (int t = 0; t < 7; ++t)
      fz = fmaf(recs[(size_t)t * NG + g], __expf(end_t[t]), fz);
    term -= logf(fz);                    // final logZ term (own vn)
    float mcf = 0.f;
    for (int cc = 0; cc < KCH; ++cc)
      mcf += recs[(size_t)15 * NG + (size_t)cc * BB + b];
    int se = (int)mcf - 1;
    int te = tags[(size_t)se * BB + b];
    term += end_t[te];                   // gold end transition
  }
  __shared__ float red[256];
  red[tid] = term;
  __syncthreads();
  for (int off = 128; off > 0; off >>= 1) {
    if (tid < off) red[tid] += red[tid + off];
    __syncthreads();
  }
  if (tid == 0) partials[blockIdx.x] = red[0];
}

// ---------------------------------------------------------------------------
// Kernel 3: deterministic tree-reduce of the block partials.
// ---------------------------------------------------------------------------
__global__ __launch_bounds__(1024)
void crf_reduce_kernel(const float* __restrict__ partials, int n,
                       float* __restrict__ out) {
  __shared__ float s[1024];
  int t = threadIdx.x;
  float v = 0.f;
  for (int i = t; i < n; i += 1024) v += partials[i];
  s[t] = v;
  __syncthreads();
  for (int off = 512; off > 0; off >>= 1) {
    if (t < off) s[t] += s[t + off];
    __syncthreads();
  }
  if (t == 0) out[0] = s[0];
}

extern "C" void kernel_launch(void* const* d_in, const int* in_sizes, int n_in,
                              void* d_out, int out_size, void* d_ws, size_t ws_size,
                              hipStream_t stream) {
  const float* em      = (const float*)d_in[0];
  const int*   tags    = (const int*)d_in[1];
  const int*   qmask   = (const int*)d_in[2];
  const int*   mask    = (const int*)d_in[3];
  const float* start_t = (const float*)d_in[4];
  const float* end_t   = (const float*)d_in[5];
  const float* self_t  = (const float*)d_in[6];
  const float* other_t = (const float*)d_in[7];

  float* recs = (float*)d_ws;

  auto need = [](int kch) {
    size_t ng = (size_t)kch * BB;
    return (NFLD * ng + ng / 256) * sizeof(float);
  };

  if (ws_size >= need(128)) {
    constexpr int KCH = 128;   // CC=16; 8192 waves = 32/CU (HW max)
    constexpr int NG  = KCH * BB;
    float* partials = recs + (size_t)NFLD * NG;
    int fwd_blocks = NG / 256;          // 1024 -> 4096 fwd waves
    int bwd_blocks = NG / 256;          // 1024 -> 4096 bwd waves
    crf_chunk_kernel<KCH><<<fwd_blocks + bwd_blocks, 256, 0, stream>>>(
        em, tags, qmask, mask, self_t, other_t, recs);
    crf_junction_kernel<KCH><<<NG / 256, 256, 0, stream>>>(
        recs, em, tags, start_t, end_t, partials);
    crf_reduce_kernel<<<1, 1024, 0, stream>>>(partials, NG / 256, (float*)d_out);
  } else {
    constexpr int KCH = 64;    // fallback (R21 champion config)
    constexpr int NG  = KCH * BB;
    float* partials = recs + (size_t)NFLD * NG;
    int fwd_blocks = NG / 256;
    int bwd_blocks = NG / 256;
    crf_chunk_kernel<KCH><<<fwd_blocks + bwd_blocks, 256, 0, stream>>>(
        em, tags, qmask, mask, self_t, other_t, recs);
    crf_junction_kernel<KCH><<<NG / 256, 256, 0, stream>>>(
        recs, em, tags, start_t, end_t, partials);
    crf_reduce_kernel<<<1, 1024, 0, stream>>>(partials, NG / 256, (float*)d_out);
  }
}

// Round 23
// 50.894 us; speedup vs baseline: 1.1304x; 1.1304x over previous
//
#include <hip/hip_runtime.h>
#include <hip/hip_bf16.h>

#define LSEQ 2048
#define BB   2048
#define TT   7
#define NFLD 17   // SoA fields: [0..6] vn, [7..13] rn, [14] sc, [15] mc, [16] Lmass

typedef float f4 __attribute__((ext_vector_type(4)));

// Load 7 floats from a 4B-aligned row as two overlapping dwordx4 loads.
__device__ __forceinline__ void ld7(const float* __restrict__ p, float* e) {
  f4 lo, hi;
  __builtin_memcpy(&lo, p, 16);
  __builtin_memcpy(&hi, p + 3, 16);
  e[0] = lo.x; e[1] = lo.y; e[2] = lo.z; e[3] = lo.w;
  e[4] = hi.y; e[5] = hi.z; e[6] = hi.w;
}

// ---------------------------------------------------------------------------
// Rank-1 chunk decomposition, v11 = KCH=128, S=1, NB=4.
// P_c = u s v^T, s = 1^T P 1.
//   forward (CC=16 steps, 1 chunk/thread): v <- (v.E) o ee -> vn, Lmass,
//     gold sc, mask count.
//   backward (NB=4 steps, 1 chunk/thread): u DIRECTION only (0.1^4 = 1e-4
//     per junction; 262K independent terms -> summed error O(10) vs 2e5).
// MODEL (R20->R22): time = bytes/BW(waves); BW rises with waves (R22 proved
// 1.4->1.83 TB/s at 2x waves) but R22's NB=8 at CC=16 re-read HALF of em
// (+24MB = the 13us regression). NB=4 restores R21's 25% re-read while
// keeping the doubled forward wave count.
// Falsified (do not retry): LDS em tiles (R11/R18), branch-free loops (R19),
// asm rings (R14 fault), min-wave launch_bounds (R5/R7 spill).
// ---------------------------------------------------------------------------
template<int KCH>
__global__ __launch_bounds__(256)
void crf_chunk_kernel(const float* __restrict__ em,
                      const int*   __restrict__ tags,
                      const int*   __restrict__ qmask,
                      const int*   __restrict__ mask,
                      const float* __restrict__ self_t,
                      const float* __restrict__ other_t,
                      float* __restrict__ recs) {
  constexpr int CC   = LSEQ / KCH;
  constexpr int NG   = KCH * BB;
  constexpr int NB   = (CC < 4) ? CC : 4;   // backward steps for u direction
  constexpr int NFWD = NG / 256;            // forward blocks
  __shared__ float sE[2][49];        // exp(transitions): [0]=self, [1]=other
  __shared__ float sT[2][49];        // raw transitions (gold-path score)
  int tid = threadIdx.x;
  if (tid < 49) {
    float sv = self_t[tid], ov = other_t[tid];
    sE[0][tid] = __expf(sv); sE[1][tid] = __expf(ov);
    sT[0][tid] = sv;         sT[1][tid] = ov;
  }
  __syncthreads();

  float Es[49];                      // SGPR-resident via readfirstlane
  int loadedCont = -1;
  auto loadEs = [&](int cf) {
#pragma unroll
    for (int k = 0; k < 49; ++k)
      Es[k] = __int_as_float(
          __builtin_amdgcn_readfirstlane(__float_as_int(sE[cf][k])));
    loadedCont = cf;
  };

  int bid = blockIdx.x;
  if (bid < NFWD) {
    // ============ forward: vn, Lmass, gold score (1 chunk/thread) =========
    int g = bid * 256 + tid;
    int b = g & (BB - 1);
    int c = g >> 11;                 // uniform per block (256 | 2048)
    float v[7] = {1.f,1.f,1.f,1.f,1.f,1.f,1.f};
    float sc = 0.f, Lv = 0.f;
    int mc = 0, tp, qp;
    int i0 = c * CC;
    if (c == 0) { mc = mask[b]; tp = tags[b]; qp = qmask[b]; }
    else { size_t pb = (size_t)(i0 - 1) * BB + b; tp = tags[pb]; qp = qmask[pb]; }

    auto LDF = [&](int s, float* e, int& tg, int& qm, int& mi) {
      size_t base = (size_t)(i0 + s) * BB + b;
      ld7(em + base * TT, e);
      tg = tags[base]; qm = qmask[base]; mi = mask[base];
    };

    float e0[7], e1[7];
    int tg0, qm0, mi0, tg1, qm1, mi1;
    LDF(0, e0, tg0, qm0, mi0);

    for (int j = 0; j < CC; ++j) {
      bool more = (j + 1 < CC);                   // wave-uniform
      if (more) LDF(j + 1, e1, tg1, qm1, mi1);    // issue next-step loads

      int mi = (c == 0 && j == 0) ? 0 : mi0;      // boundary step = identity
      int cont = (qm0 != qp) ? 1 : 0;
      int cf = __builtin_amdgcn_readfirstlane(cont);
      bool uni = __all(cont == cf);
      float ee[7];
#pragma unroll
      for (int t = 0; t < 7; ++t) ee[t] = __expf(e0[t]);
      float etag = e0[0];
#pragma unroll
      for (int t = 1; t < 7; ++t) etag = (tg0 == t) ? e0[t] : etag;
      float ttag = sT[cont][tp * 7 + tg0];
      if (mi) { sc += ttag + etag; ++mc; }
      tp = tg0; qp = qm0;

      float a[7] = {0.f,0.f,0.f,0.f,0.f,0.f,0.f};
      if (uni) {
        if (cf != loadedCont) loadEs(cf);
#pragma unroll
        for (int r = 0; r < 7; ++r) {
          float vr = v[r];
#pragma unroll
          for (int t = 0; t < 7; ++t) a[t] = fmaf(vr, Es[r*7+t], a[t]);
        }
      } else {
        loadedCont = -1;
#pragma unroll
        for (int r = 0; r < 7; ++r) {
          float vr = v[r];
#pragma unroll
          for (int t = 0; t < 7; ++t) a[t] = fmaf(vr, sE[cont][r*7+t], a[t]);
        }
      }
#pragma unroll
      for (int t = 0; t < 7; ++t) v[t] = mi ? a[t] * ee[t] : v[t];

      if ((j & 7) == 7) {                         // renorm, track log mass
        float ss = v[0]+v[1]+v[2]+v[3]+v[4]+v[5]+v[6];
        Lv += logf(ss);
        float inv = 1.0f / ss;
#pragma unroll
        for (int t = 0; t < 7; ++t) v[t] *= inv;
      }
      if (more) {
#pragma unroll
        for (int t = 0; t < 7; ++t) e0[t] = e1[t];
        tg0 = tg1; qm0 = qm1; mi0 = mi1;
      }
    }
    float ss = v[0]+v[1]+v[2]+v[3]+v[4]+v[5]+v[6];
    float inv = 1.0f / ss;
#pragma unroll
    for (int t = 0; t < 7; ++t) recs[(size_t)t * NG + g] = v[t] * inv;
    recs[(size_t)14 * NG + g] = sc;
    recs[(size_t)15 * NG + g] = (float)mc;
    recs[(size_t)16 * NG + g] = Lv + logf(ss);    // Lmass = log(1^T P 1)
  } else {
    // ============ backward: u direction, NB steps (1 chunk/thread) ========
    int g = (bid - NFWD) * 256 + tid;
    int b = g & (BB - 1);
    int c = g >> 11;
    float r[7] = {1.f,1.f,1.f,1.f,1.f,1.f,1.f};
    int ilo = (c == 0) ? 1 : c * CC;

    auto LDB = [&](int s, float* e, int& q, int& q1, int& mi2) {
      size_t base = (size_t)(ilo + NB - 1 - s) * BB + b;    // i >= 1
      ld7(em + base * TT, e);
      q = qmask[base]; q1 = qmask[base - BB]; mi2 = mask[base];
    };

    float e0[7], e1[7];
    int q0, q10, m0, q1v, q11, m1;
    LDB(0, e0, q0, q10, m0);

    for (int j = 0; j < NB; ++j) {
      bool more = (j + 1 < NB);
      if (more) LDB(j + 1, e1, q1v, q11, m1);

      int cont = (q0 != q10) ? 1 : 0;
      int cf = __builtin_amdgcn_readfirstlane(cont);
      bool uni = __all(cont == cf);
      float ee[7];
#pragma unroll
      for (int t = 0; t < 7; ++t) ee[t] = __expf(e0[t]);
      float tmp[7];
#pragma unroll
      for (int t = 0; t < 7; ++t) tmp[t] = ee[t] * r[t];
      float a[7] = {0.f,0.f,0.f,0.f,0.f,0.f,0.f};
      if (uni) {
        if (cf != loadedCont) loadEs(cf);
#pragma unroll
        for (int t = 0; t < 7; ++t) {
          float tt = tmp[t];
#pragma unroll
          for (int s2 = 0; s2 < 7; ++s2) a[s2] = fmaf(tt, Es[s2*7+t], a[s2]);
        }
      } else {
        loadedCont = -1;
#pragma unroll
        for (int t = 0; t < 7; ++t) {
          float tt = tmp[t];
#pragma unroll
          for (int s2 = 0; s2 < 7; ++s2) a[s2] = fmaf(tt, sE[cont][s2*7+t], a[s2]);
        }
      }
#pragma unroll
      for (int s2 = 0; s2 < 7; ++s2) r[s2] = m0 ? a[s2] : r[s2];

      if (more) {
#pragma unroll
        for (int t = 0; t < 7; ++t) e0[t] = e1[t];
        q0 = q1v; q10 = q11; m0 = m1;
      }
    }
    float ss = r[0]+r[1]+r[2]+r[3]+r[4]+r[5]+r[6];
    float inv = 1.0f / ss;
#pragma unroll
    for (int t = 0; t < 7; ++t) recs[(size_t)(7 + t) * NG + g] = r[t] * inv;
  }
}

// ---------------------------------------------------------------------------
// Kernel 2: flat-parallel junction terms + per-block tree reduction.
// term(b,c) = sc - Lmass - log(dot); dot_0 = alpha0.rn_0 (+gold start terms),
// dot_c = vn_{c-1}.rn_c; c==KCH-1 folds the final logZ term and gold end.
// ---------------------------------------------------------------------------
template<int KCH>
__global__ __launch_bounds__(256)
void crf_junction_kernel(const float* __restrict__ recs,
                         const float* __restrict__ em,
                         const int*   __restrict__ tags,
                         const float* __restrict__ start_t,
                         const float* __restrict__ end_t,
                         float* __restrict__ partials) {
  constexpr int NG = KCH * BB;
  int tid = threadIdx.x;
  int g = blockIdx.x * 256 + tid;
  int b = g & (BB - 1);
  int c = g >> 11;                       // block-uniform (256 | 2048)
  float rn[7];
#pragma unroll
  for (int t = 0; t < 7; ++t) rn[t] = recs[(size_t)(7 + t) * NG + g];
  float term = recs[(size_t)14 * NG + g] - recs[(size_t)16 * NG + g];
  float dot = 0.f;
  if (c == 0) {
    float e0[7], st[7];
#pragma unroll
    for (int t = 0; t < 7; ++t) { e0[t] = em[(size_t)b * TT + t]; st[t] = start_t[t]; }
#pragma unroll
    for (int t = 0; t < 7; ++t) dot = fmaf(__expf(st[t] + e0[t]), rn[t], dot);
    int tg0 = tags[b];
    float em0t = e0[0], stt = st[0];
#pragma unroll
    for (int t = 1; t < 7; ++t) {
      em0t = (tg0 == t) ? e0[t] : em0t;
      stt  = (tg0 == t) ? st[t] : stt;
    }
    term += stt + em0t;                  // gold start + em[0][tag0]
  } else {
#pragma unroll
    for (int t = 0; t < 7; ++t)
      dot = fmaf(recs[(size_t)t * NG + (g - BB)], rn[t], dot);
  }
  term -= logf(dot);
  if (c == KCH - 1) {
    float fz = 0.f;
#pragma unroll
    for (int t = 0; t < 7; ++t)
      fz = fmaf(recs[(size_t)t * NG + g], __expf(end_t[t]), fz);
    term -= logf(fz);                    // final logZ term (own vn)
    float mcf = 0.f;
    for (int cc = 0; cc < KCH; ++cc)
      mcf += recs[(size_t)15 * NG + (size_t)cc * BB + b];
    int se = (int)mcf - 1;
    int te = tags[(size_t)se * BB + b];
    term += end_t[te];                   // gold end transition
  }
  __shared__ float red[256];
  red[tid] = term;
  __syncthreads();
  for (int off = 128; off > 0; off >>= 1) {
    if (tid < off) red[tid] += red[tid + off];
    __syncthreads();
  }
  if (tid == 0) partials[blockIdx.x] = red[0];
}

// ---------------------------------------------------------------------------
// Kernel 3: deterministic tree-reduce of the block partials.
// ---------------------------------------------------------------------------
__global__ __launch_bounds__(1024)
void crf_reduce_kernel(const float* __restrict__ partials, int n,
                       float* __restrict__ out) {
  __shared__ float s[1024];
  int t = threadIdx.x;
  float v = 0.f;
  for (int i = t; i < n; i += 1024) v += partials[i];
  s[t] = v;
  __syncthreads();
  for (int off = 512; off > 0; off >>= 1) {
    if (t < off) s[t] += s[t + off];
    __syncthreads();
  }
  if (t == 0) out[0] = s[0];
}

extern "C" void kernel_launch(void* const* d_in, const int* in_sizes, int n_in,
                              void* d_out, int out_size, void* d_ws, size_t ws_size,
                              hipStream_t stream) {
  const float* em      = (const float*)d_in[0];
  const int*   tags    = (const int*)d_in[1];
  const int*   qmask   = (const int*)d_in[2];
  const int*   mask    = (const int*)d_in[3];
  const float* start_t = (const float*)d_in[4];
  const float* end_t   = (const float*)d_in[5];
  const float* self_t  = (const float*)d_in[6];
  const float* other_t = (const float*)d_in[7];

  float* recs = (float*)d_ws;

  auto need = [](int kch) {
    size_t ng = (size_t)kch * BB;
    return (NFLD * ng + ng / 256) * sizeof(float);
  };

  if (ws_size >= need(128)) {
    constexpr int KCH = 128;   // CC=16; 8192 waves, backward reads 4/16 rows
    constexpr int NG  = KCH * BB;
    float* partials = recs + (size_t)NFLD * NG;
    int fwd_blocks = NG / 256;
    int bwd_blocks = NG / 256;
    crf_chunk_kernel<KCH><<<fwd_blocks + bwd_blocks, 256, 0, stream>>>(
        em, tags, qmask, mask, self_t, other_t, recs);
    crf_junction_kernel<KCH><<<NG / 256, 256, 0, stream>>>(
        recs, em, tags, start_t, end_t, partials);
    crf_reduce_kernel<<<1, 1024, 0, stream>>>(partials, NG / 256, (float*)d_out);
  } else {
    constexpr int KCH = 64;    // fallback
    constexpr int NG  = KCH * BB;
    float* partials = recs + (size_t)NFLD * NG;
    int fwd_blocks = NG / 256;
    int bwd_blocks = NG / 256;
    crf_chunk_kernel<KCH><<<fwd_blocks + bwd_blocks, 256, 0, stream>>>(
        em, tags, qmask, mask, self_t, other_t, recs);
    crf_junction_kernel<KCH><<<NG / 256, 256, 0, stream>>>(
        recs, em, tags, start_t, end_t, partials);
    crf_reduce_kernel<<<1, 1024, 0, stream>>>(partials, NG / 256, (float*)d_out);
  }
}

// Round 24
// 48.300 us; speedup vs baseline: 1.1911x; 1.0537x over previous
//
#include <hip/hip_runtime.h>
#include <hip/hip_bf16.h>

#define LSEQ 2048
#define BB   2048
#define TT   7
#define NFLD 17   // SoA fields: [0..6] vn, [7..13] rn, [14] sc, [15] mc, [16] Lmass

typedef float f4 __attribute__((ext_vector_type(4)));

// Load 7 floats from a 4B-aligned row as two overlapping dwordx4 loads.
__device__ __forceinline__ void ld7(const float* __restrict__ p, float* e) {
  f4 lo, hi;
  __builtin_memcpy(&lo, p, 16);
  __builtin_memcpy(&hi, p + 3, 16);
  e[0] = lo.x; e[1] = lo.y; e[2] = lo.z; e[3] = lo.w;
  e[4] = hi.y; e[5] = hi.z; e[6] = hi.w;
}

// ---------------------------------------------------------------------------
// Rank-1 chunk decomposition, v12: FUSED u-replay (no backward role at all).
// P_c = u s v^T, s = 1^T P 1.
//   forward (CC steps, 1 chunk/thread): v <- (v.E) o ee -> vn, Lmass, gold
//     sc, mask count. The FIRST NB=4 rows are buffered in registers
//     (statically indexed via unrolled phase-A) as they stream through.
//   u-replay (NB=4 steps, same thread, zero loads): r <- E.(ee o r) over the
//     buffered rows in reverse -> rn (u direction, 1e-4/junction; R23
//     validated NB=4 at absmax 0).
// MODEL: wave->BW saturates at ~4096 waves (R23: 8192 waves no faster).
// R21's remaining slack was the backward role's 4096 waves + ~40MB re-reads;
// fusing eliminates both. Grid = 4096 fwd waves (KCH=128), bytes = unique
// 167MB only.
// Falsified (do not retry): LDS em tiles (R11/R18), branch-free loops (R19),
// asm rings (R14 fault), min-wave launch_bounds (R5/R7 spill), >4096 waves
// (R23).
// ---------------------------------------------------------------------------
template<int KCH>
__global__ __launch_bounds__(256)
void crf_chunk_kernel(const float* __restrict__ em,
                      const int*   __restrict__ tags,
                      const int*   __restrict__ qmask,
                      const int*   __restrict__ mask,
                      const float* __restrict__ self_t,
                      const float* __restrict__ other_t,
                      float* __restrict__ recs) {
  constexpr int CC = LSEQ / KCH;
  constexpr int NG = KCH * BB;
  constexpr int NB = (CC < 4) ? CC : 4;   // buffered rows for the u-replay
  __shared__ float sE[2][49];        // exp(transitions): [0]=self, [1]=other
  __shared__ float sT[2][49];        // raw transitions (gold-path score)
  int tid = threadIdx.x;
  if (tid < 49) {
    float sv = self_t[tid], ov = other_t[tid];
    sE[0][tid] = __expf(sv); sE[1][tid] = __expf(ov);
    sT[0][tid] = sv;         sT[1][tid] = ov;
  }
  __syncthreads();

  float Es[49];                      // SGPR-resident via readfirstlane
  int loadedCont = -1;
  auto loadEs = [&](int cf) {
#pragma unroll
    for (int k = 0; k < 49; ++k)
      Es[k] = __int_as_float(
          __builtin_amdgcn_readfirstlane(__float_as_int(sE[cf][k])));
    loadedCont = cf;
  };

  int g = blockIdx.x * 256 + tid;
  int b = g & (BB - 1);
  int c = g >> 11;                   // uniform per block (256 | 2048)
  float v[7] = {1.f,1.f,1.f,1.f,1.f,1.f,1.f};
  float sc = 0.f, Lv = 0.f;
  int mc = 0, tp, qp;
  int i0 = c * CC;
  if (c == 0) { mc = mask[b]; tp = tags[b]; qp = qmask[b]; }
  else { size_t pb = (size_t)(i0 - 1) * BB + b; tp = tags[pb]; qp = qmask[pb]; }

  auto LDF = [&](int s, float* e, int& tg, int& qm, int& mi) {
    size_t base = (size_t)(i0 + s) * BB + b;
    ld7(em + base * TT, e);
    tg = tags[base]; qm = qmask[base]; mi = mask[base];
  };

  // u-replay buffers — statically indexed only (phase-A unrolled; rule #20)
  float ub[NB][7];
  int ucont[NB], umask[NB];

  float e0[7], e1[7];
  int tg0, qm0, mi0, tg1, qm1, mi1;
  LDF(0, e0, tg0, qm0, mi0);

  // One step of the forward recurrence (shared by both phases).
  auto FSTEP = [&](const float* e, int tg, int qm, int mi, int& contOut) {
    int cont = (qm != qp) ? 1 : 0;
    contOut = cont;
    int cf = __builtin_amdgcn_readfirstlane(cont);
    bool uni = __all(cont == cf);
    float ee[7];
#pragma unroll
    for (int t = 0; t < 7; ++t) ee[t] = __expf(e[t]);
    float etag = e[0];
#pragma unroll
    for (int t = 1; t < 7; ++t) etag = (tg == t) ? e[t] : etag;
    float ttag = sT[cont][tp * 7 + tg];
    if (mi) { sc += ttag + etag; ++mc; }
    tp = tg; qp = qm;
    float a[7] = {0.f,0.f,0.f,0.f,0.f,0.f,0.f};
    if (uni) {
      if (cf != loadedCont) loadEs(cf);
#pragma unroll
      for (int r = 0; r < 7; ++r) {
        float vr = v[r];
#pragma unroll
        for (int t = 0; t < 7; ++t) a[t] = fmaf(vr, Es[r*7+t], a[t]);
      }
    } else {
      loadedCont = -1;
#pragma unroll
      for (int r = 0; r < 7; ++r) {
        float vr = v[r];
#pragma unroll
        for (int t = 0; t < 7; ++t) a[t] = fmaf(vr, sE[cont][r*7+t], a[t]);
      }
    }
#pragma unroll
    for (int t = 0; t < 7; ++t) v[t] = mi ? a[t] * ee[t] : v[t];
  };

  // ---- phase A: first NB steps, unrolled, buffering rows for the replay --
#pragma unroll
  for (int j = 0; j < NB; ++j) {
    LDF(j + 1, e1, tg1, qm1, mi1);            // NB < CC so j+1 is valid
    int mi = (c == 0 && j == 0) ? 0 : mi0;    // boundary step = identity
#pragma unroll
    for (int t = 0; t < 7; ++t) ub[j][t] = e0[t];
    umask[j] = mi;
    int contOut;
    FSTEP(e0, tg0, qm0, mi, contOut);
    ucont[j] = contOut;
#pragma unroll
    for (int t = 0; t < 7; ++t) e0[t] = e1[t];
    tg0 = tg1; qm0 = qm1; mi0 = mi1;
  }

  // ---- phase B: remaining steps, runtime loop with depth-1 prefetch ------
  for (int j = NB; j < CC; ++j) {
    bool more = (j + 1 < CC);                 // wave-uniform
    if (more) LDF(j + 1, e1, tg1, qm1, mi1);
    int contOut;
    FSTEP(e0, tg0, qm0, mi0, contOut);
    if ((j & 7) == 7) {                       // renorm, track log mass
      float ss = v[0]+v[1]+v[2]+v[3]+v[4]+v[5]+v[6];
      Lv += logf(ss);
      float inv = 1.0f / ss;
#pragma unroll
      for (int t = 0; t < 7; ++t) v[t] *= inv;
    }
    if (more) {
#pragma unroll
      for (int t = 0; t < 7; ++t) e0[t] = e1[t];
      tg0 = tg1; qm0 = qm1; mi0 = mi1;
    }
  }

  // ---- epilogue: vn record ----
  float ss = v[0]+v[1]+v[2]+v[3]+v[4]+v[5]+v[6];
  float inv = 1.0f / ss;
#pragma unroll
  for (int t = 0; t < 7; ++t) recs[(size_t)t * NG + g] = v[t] * inv;
  recs[(size_t)14 * NG + g] = sc;
  recs[(size_t)15 * NG + g] = (float)mc;
  recs[(size_t)16 * NG + g] = Lv + logf(ss);  // Lmass = log(1^T P 1)

  // ---- u-replay: reverse over the buffered rows, zero memory traffic ----
  float r[7] = {1.f,1.f,1.f,1.f,1.f,1.f,1.f};
#pragma unroll
  for (int jj = NB - 1; jj >= 0; --jj) {
    int cont = ucont[jj], mi = umask[jj];
    int cf = __builtin_amdgcn_readfirstlane(cont);
    bool uni = __all(cont == cf);
    float ee[7];
#pragma unroll
    for (int t = 0; t < 7; ++t) ee[t] = __expf(ub[jj][t]);
    float tmp[7];
#pragma unroll
    for (int t = 0; t < 7; ++t) tmp[t] = ee[t] * r[t];
    float a[7] = {0.f,0.f,0.f,0.f,0.f,0.f,0.f};
    if (uni) {
      if (cf != loadedCont) loadEs(cf);
#pragma unroll
      for (int t = 0; t < 7; ++t) {
        float tt = tmp[t];
#pragma unroll
        for (int s2 = 0; s2 < 7; ++s2) a[s2] = fmaf(tt, Es[s2*7+t], a[s2]);
      }
    } else {
      loadedCont = -1;
#pragma unroll
      for (int t = 0; t < 7; ++t) {
        float tt = tmp[t];
#pragma unroll
        for (int s2 = 0; s2 < 7; ++s2) a[s2] = fmaf(tt, sE[cont][s2*7+t], a[s2]);
      }
    }
#pragma unroll
    for (int s2 = 0; s2 < 7; ++s2) r[s2] = mi ? a[s2] : r[s2];
  }
  float sr = r[0]+r[1]+r[2]+r[3]+r[4]+r[5]+r[6];
  float invr = 1.0f / sr;
#pragma unroll
  for (int t = 0; t < 7; ++t) recs[(size_t)(7 + t) * NG + g] = r[t] * invr;
}

// ---------------------------------------------------------------------------
// Kernel 2: flat-parallel junction terms + per-block tree reduction.
// term(b,c) = sc - Lmass - log(dot); dot_0 = alpha0.rn_0 (+gold start terms),
// dot_c = vn_{c-1}.rn_c; c==KCH-1 folds the final logZ term and gold end.
// ---------------------------------------------------------------------------
template<int KCH>
__global__ __launch_bounds__(256)
void crf_junction_kernel(const float* __restrict__ recs,
                         const float* __restrict__ em,
                         const int*   __restrict__ tags,
                         const float* __restrict__ start_t,
                         const float* __restrict__ end_t,
                         float* __restrict__ partials) {
  constexpr int NG = KCH * BB;
  int tid = threadIdx.x;
  int g = blockIdx.x * 256 + tid;
  int b = g & (BB - 1);
  int c = g >> 11;                       // block-uniform (256 | 2048)
  float rn[7];
#pragma unroll
  for (int t = 0; t < 7; ++t) rn[t] = recs[(size_t)(7 + t) * NG + g];
  float term = recs[(size_t)14 * NG + g] - recs[(size_t)16 * NG + g];
  float dot = 0.f;
  if (c == 0) {
    float e0[7], st[7];
#pragma unroll
    for (int t = 0; t < 7; ++t) { e0[t] = em[(size_t)b * TT + t]; st[t] = start_t[t]; }
#pragma unroll
    for (int t = 0; t < 7; ++t) dot = fmaf(__expf(st[t] + e0[t]), rn[t], dot);
    int tg0 = tags[b];
    float em0t = e0[0], stt = st[0];
#pragma unroll
    for (int t = 1; t < 7; ++t) {
      em0t = (tg0 == t) ? e0[t] : em0t;
      stt  = (tg0 == t) ? st[t] : stt;
    }
    term += stt + em0t;                  // gold start + em[0][tag0]
  } else {
#pragma unroll
    for (int t = 0; t < 7; ++t)
      dot = fmaf(recs[(size_t)t * NG + (g - BB)], rn[t], dot);
  }
  term -= logf(dot);
  if (c == KCH - 1) {
    float fz = 0.f;
#pragma unroll
    for (int t = 0; t < 7; ++t)
      fz = fmaf(recs[(size_t)t * NG + g], __expf(end_t[t]), fz);
    term -= logf(fz);                    // final logZ term (own vn)
    float mcf = 0.f;
    for (int cc = 0; cc < KCH; ++cc)
      mcf += recs[(size_t)15 * NG + (size_t)cc * BB + b];
    int se = (int)mcf - 1;
    int te = tags[(size_t)se * BB + b];
    term += end_t[te];                   // gold end transition
  }
  __shared__ float red[256];
  red[tid] = term;
  __syncthreads();
  for (int off = 128; off > 0; off >>= 1) {
    if (tid < off) red[tid] += red[tid + off];
    __syncthreads();
  }
  if (tid == 0) partials[blockIdx.x] = red[0];
}

// ---------------------------------------------------------------------------
// Kernel 3: deterministic tree-reduce of the block partials.
// ---------------------------------------------------------------------------
__global__ __launch_bounds__(1024)
void crf_reduce_kernel(const float* __restrict__ partials, int n,
                       float* __restrict__ out) {
  __shared__ float s[1024];
  int t = threadIdx.x;
  float v = 0.f;
  for (int i = t; i < n; i += 1024) v += partials[i];
  s[t] = v;
  __syncthreads();
  for (int off = 512; off > 0; off >>= 1) {
    if (t < off) s[t] += s[t + off];
    __syncthreads();
  }
  if (t == 0) out[0] = s[0];
}

extern "C" void kernel_launch(void* const* d_in, const int* in_sizes, int n_in,
                              void* d_out, int out_size, void* d_ws, size_t ws_size,
                              hipStream_t stream) {
  const float* em      = (const float*)d_in[0];
  const int*   tags    = (const int*)d_in[1];
  const int*   qmask   = (const int*)d_in[2];
  const int*   mask    = (const int*)d_in[3];
  const float* start_t = (const float*)d_in[4];
  const float* end_t   = (const float*)d_in[5];
  const float* self_t  = (const float*)d_in[6];
  const float* other_t = (const float*)d_in[7];

  float* recs = (float*)d_ws;

  auto need = [](int kch) {
    size_t ng = (size_t)kch * BB;
    return (NFLD * ng + ng / 256) * sizeof(float);
  };

  if (ws_size >= need(128)) {
    constexpr int KCH = 128;   // CC=16; 4096 fwd waves, zero backward traffic
    constexpr int NG  = KCH * BB;
    float* partials = recs + (size_t)NFLD * NG;
    crf_chunk_kernel<KCH><<<NG / 256, 256, 0, stream>>>(
        em, tags, qmask, mask, self_t, other_t, recs);
    crf_junction_kernel<KCH><<<NG / 256, 256, 0, stream>>>(
        recs, em, tags, start_t, end_t, partials);
    crf_reduce_kernel<<<1, 1024, 0, stream>>>(partials, NG / 256, (float*)d_out);
  } else {
    constexpr int KCH = 64;    // fallback, same fused structure
    constexpr int NG  = KCH * BB;
    float* partials = recs + (size_t)NFLD * NG;
    crf_chunk_kernel<KCH><<<NG / 256, 256, 0, stream>>>(
        em, tags, qmask, mask, self_t, other_t, recs);
    crf_junction_kernel<KCH><<<NG / 256, 256, 0, stream>>>(
        recs, em, tags, start_t, end_t, partials);
    crf_reduce_kernel<<<1, 1024, 0, stream>>>(partials, NG / 256, (float*)d_out);
  }
}

// Round 25
// 42.412 us; speedup vs baseline: 1.3565x; 1.1388x over previous
//
#include <hip/hip_runtime.h>
#include <hip/hip_bf16.h>

#define LSEQ 2048
#define BB   2048
#define TT   7
#define NFLD 17   // SoA fields: [0..6] vn, [7..13] rn, [14] sc, [15] mc, [16] Lmass

typedef float f4 __attribute__((ext_vector_type(4)));

// Load 7 floats from a 4B-aligned row as two overlapping dwordx4 loads.
__device__ __forceinline__ void ld7(const float* __restrict__ p, float* e) {
  f4 lo, hi;
  __builtin_memcpy(&lo, p, 16);
  __builtin_memcpy(&hi, p + 3, 16);
  e[0] = lo.x; e[1] = lo.y; e[2] = lo.z; e[3] = lo.w;
  e[4] = hi.y; e[5] = hi.z; e[6] = hi.w;
}

// ---------------------------------------------------------------------------
// Rank-1 chunk decomposition, v13 = R21 champion + NB=4 + carried qmask.
// P_c = u s v^T, s = 1^T P 1.
//   forward (CC=32 steps, 1 chunk/thread): v <- (v.E) o ee -> vn, Lmass,
//     gold sc, mask count.
//   backward (NB=4 steps, 1 chunk/thread): u DIRECTION only (0.1^4=1e-4 per
//     junction, validated absmax 0 in R23/R24); qmask carried step-to-step
//     (one load/step instead of two).
// MODEL (R20-R24): time = bytes / ~2.4 TB/s effective (ceiling for this
// 28B-stride pattern, saturated at >=4096 waves). R24 proved backward
// re-reads are cache-hits; fusing them away bought nothing. This config is
// the minimum-bytes minimum-steps instance of the validated structure.
// Falsified (do not retry): LDS em tiles (R11/R18), branch-free loops (R19),
// asm rings (R14 fault), min-wave launch_bounds (R5/R7 spill), >4096 waves
// (R23), fused u-replay (R24).
// ---------------------------------------------------------------------------
template<int KCH>
__global__ __launch_bounds__(256)
void crf_chunk_kernel(const float* __restrict__ em,
                      const int*   __restrict__ tags,
                      const int*   __restrict__ qmask,
                      const int*   __restrict__ mask,
                      const float* __restrict__ self_t,
                      const float* __restrict__ other_t,
                      float* __restrict__ recs) {
  constexpr int CC   = LSEQ / KCH;   // 32
  constexpr int NG   = KCH * BB;
  constexpr int NB   = (CC < 4) ? CC : 4;   // backward steps for u direction
  constexpr int NFWD = NG / 256;     // forward blocks (512)
  __shared__ float sE[2][49];        // exp(transitions): [0]=self, [1]=other
  __shared__ float sT[2][49];        // raw transitions (gold-path score)
  int tid = threadIdx.x;
  if (tid < 49) {
    float sv = self_t[tid], ov = other_t[tid];
    sE[0][tid] = __expf(sv); sE[1][tid] = __expf(ov);
    sT[0][tid] = sv;         sT[1][tid] = ov;
  }
  __syncthreads();

  float Es[49];                      // SGPR-resident via readfirstlane
  int loadedCont = -1;
  auto loadEs = [&](int cf) {
#pragma unroll
    for (int k = 0; k < 49; ++k)
      Es[k] = __int_as_float(
          __builtin_amdgcn_readfirstlane(__float_as_int(sE[cf][k])));
    loadedCont = cf;
  };

  int bid = blockIdx.x;
  if (bid < NFWD) {
    // ============ forward: vn, Lmass, gold score (1 chunk/thread) =========
    int g = bid * 256 + tid;
    int b = g & (BB - 1);
    int c = g >> 11;                 // uniform per block (256 | 2048)
    float v[7] = {1.f,1.f,1.f,1.f,1.f,1.f,1.f};
    float sc = 0.f, Lv = 0.f;
    int mc = 0, tp, qp;
    int i0 = c * CC;
    if (c == 0) { mc = mask[b]; tp = tags[b]; qp = qmask[b]; }
    else { size_t pb = (size_t)(i0 - 1) * BB + b; tp = tags[pb]; qp = qmask[pb]; }

    auto LDF = [&](int s, float* e, int& tg, int& qm, int& mi) {
      size_t base = (size_t)(i0 + s) * BB + b;
      ld7(em + base * TT, e);
      tg = tags[base]; qm = qmask[base]; mi = mask[base];
    };

    float e0[7], e1[7];
    int tg0, qm0, mi0, tg1, qm1, mi1;
    LDF(0, e0, tg0, qm0, mi0);

    for (int j = 0; j < CC; ++j) {
      bool more = (j + 1 < CC);                   // wave-uniform
      if (more) LDF(j + 1, e1, tg1, qm1, mi1);    // issue next-step loads

      int mi = (c == 0 && j == 0) ? 0 : mi0;      // boundary step = identity
      int cont = (qm0 != qp) ? 1 : 0;
      int cf = __builtin_amdgcn_readfirstlane(cont);
      bool uni = __all(cont == cf);
      float ee[7];
#pragma unroll
      for (int t = 0; t < 7; ++t) ee[t] = __expf(e0[t]);
      float etag = e0[0];
#pragma unroll
      for (int t = 1; t < 7; ++t) etag = (tg0 == t) ? e0[t] : etag;
      float ttag = sT[cont][tp * 7 + tg0];
      if (mi) { sc += ttag + etag; ++mc; }
      tp = tg0; qp = qm0;

      float a[7] = {0.f,0.f,0.f,0.f,0.f,0.f,0.f};
      if (uni) {
        if (cf != loadedCont) loadEs(cf);
#pragma unroll
        for (int r = 0; r < 7; ++r) {
          float vr = v[r];
#pragma unroll
          for (int t = 0; t < 7; ++t) a[t] = fmaf(vr, Es[r*7+t], a[t]);
        }
      } else {
        loadedCont = -1;
#pragma unroll
        for (int r = 0; r < 7; ++r) {
          float vr = v[r];
#pragma unroll
          for (int t = 0; t < 7; ++t) a[t] = fmaf(vr, sE[cont][r*7+t], a[t]);
        }
      }
#pragma unroll
      for (int t = 0; t < 7; ++t) v[t] = mi ? a[t] * ee[t] : v[t];

      if ((j & 7) == 7) {                         // renorm, track log mass
        float ss = v[0]+v[1]+v[2]+v[3]+v[4]+v[5]+v[6];
        Lv += logf(ss);
        float inv = 1.0f / ss;
#pragma unroll
        for (int t = 0; t < 7; ++t) v[t] *= inv;
      }
      if (more) {
#pragma unroll
        for (int t = 0; t < 7; ++t) e0[t] = e1[t];
        tg0 = tg1; qm0 = qm1; mi0 = mi1;
      }
    }
    float ss = v[0]+v[1]+v[2]+v[3]+v[4]+v[5]+v[6];
    float inv = 1.0f / ss;
#pragma unroll
    for (int t = 0; t < 7; ++t) recs[(size_t)t * NG + g] = v[t] * inv;
    recs[(size_t)14 * NG + g] = sc;
    recs[(size_t)15 * NG + g] = (float)mc;
    recs[(size_t)16 * NG + g] = Lv + logf(ss);    // Lmass = log(1^T P 1)
  } else {
    // ============ backward: u direction, NB steps (1 chunk/thread) ========
    int g = (bid - NFWD) * 256 + tid;
    int b = g & (BB - 1);
    int c = g >> 11;
    float r[7] = {1.f,1.f,1.f,1.f,1.f,1.f,1.f};
    int ilo = (c == 0) ? 1 : c * CC;

    // step j processes row i = ilo+NB-1-j, descending; q of step j+1 is the
    // q1 of step j, so carry it (one qmask load per step).
    auto LDE = [&](int s, float* e, int& mi2) {
      size_t base = (size_t)(ilo + NB - 1 - s) * BB + b;    // i >= 1
      ld7(em + base * TT, e);
      mi2 = mask[base];
    };
    auto LDQ1 = [&](int s) {                       // qmask[i-1] for step s
      int idx = ilo + NB - 2 - s;                  // may hit -1 at the tail
      idx = (idx > 0) ? idx : 0;                   // clamp (value unused)
      return qmask[(size_t)idx * BB + b];
    };

    float e0[7], e1[7];
    int m0, m1;
    LDE(0, e0, m0);
    int q0  = qmask[(size_t)(ilo + NB - 1) * BB + b];
    int q10 = LDQ1(0);

    for (int j = 0; j < NB; ++j) {
      bool more = (j + 1 < NB);
      int q11 = 0;
      if (more) {
        LDE(j + 1, e1, m1);
        q11 = LDQ1(j + 1);                         // carried q comes from q10
      }

      int cont = (q0 != q10) ? 1 : 0;
      int cf = __builtin_amdgcn_readfirstlane(cont);
      bool uni = __all(cont == cf);
      float ee[7];
#pragma unroll
      for (int t = 0; t < 7; ++t) ee[t] = __expf(e0[t]);
      float tmp[7];
#pragma unroll
      for (int t = 0; t < 7; ++t) tmp[t] = ee[t] * r[t];
      float a[7] = {0.f,0.f,0.f,0.f,0.f,0.f,0.f};
      if (uni) {
        if (cf != loadedCont) loadEs(cf);
#pragma unroll
        for (int t = 0; t < 7; ++t) {
          float tt = tmp[t];
#pragma unroll
          for (int s2 = 0; s2 < 7; ++s2) a[s2] = fmaf(tt, Es[s2*7+t], a[s2]);
        }
      } else {
        loadedCont = -1;
#pragma unroll
        for (int t = 0; t < 7; ++t) {
          float tt = tmp[t];
#pragma unroll
          for (int s2 = 0; s2 < 7; ++s2) a[s2] = fmaf(tt, sE[cont][s2*7+t], a[s2]);
        }
      }
#pragma unroll
      for (int s2 = 0; s2 < 7; ++s2) r[s2] = m0 ? a[s2] : r[s2];

      if (more) {
#pragma unroll
        for (int t = 0; t < 7; ++t) e0[t] = e1[t];
        q0 = q10; q10 = q11; m0 = m1;
      }
    }
    float ss = r[0]+r[1]+r[2]+r[3]+r[4]+r[5]+r[6];
    float inv = 1.0f / ss;
#pragma unroll
    for (int t = 0; t < 7; ++t) recs[(size_t)(7 + t) * NG + g] = r[t] * inv;
  }
}

// ---------------------------------------------------------------------------
// Kernel 2: flat-parallel junction terms + per-block tree reduction.
// term(b,c) = sc - Lmass - log(dot); dot_0 = alpha0.rn_0 (+gold start terms),
// dot_c = vn_{c-1}.rn_c; c==KCH-1 folds the final logZ term and gold end.
// ---------------------------------------------------------------------------
template<int KCH>
__global__ __launch_bounds__(256)
void crf_junction_kernel(const float* __restrict__ recs,
                         const float* __restrict__ em,
                         const int*   __restrict__ tags,
                         const float* __restrict__ start_t,
                         const float* __restrict__ end_t,
                         float* __restrict__ partials) {
  constexpr int NG = KCH * BB;
  int tid = threadIdx.x;
  int g = blockIdx.x * 256 + tid;
  int b = g & (BB - 1);
  int c = g >> 11;                       // block-uniform (256 | 2048)
  float rn[7];
#pragma unroll
  for (int t = 0; t < 7; ++t) rn[t] = recs[(size_t)(7 + t) * NG + g];
  float term = recs[(size_t)14 * NG + g] - recs[(size_t)16 * NG + g];
  float dot = 0.f;
  if (c == 0) {
    float e0[7], st[7];
#pragma unroll
    for (int t = 0; t < 7; ++t) { e0[t] = em[(size_t)b * TT + t]; st[t] = start_t[t]; }
#pragma unroll
    for (int t = 0; t < 7; ++t) dot = fmaf(__expf(st[t] + e0[t]), rn[t], dot);
    int tg0 = tags[b];
    float em0t = e0[0], stt = st[0];
#pragma unroll
    for (int t = 1; t < 7; ++t) {
      em0t = (tg0 == t) ? e0[t] : em0t;
      stt  = (tg0 == t) ? st[t] : stt;
    }
    term += stt + em0t;                  // gold start + em[0][tag0]
  } else {
#pragma unroll
    for (int t = 0; t < 7; ++t)
      dot = fmaf(recs[(size_t)t * NG + (g - BB)], rn[t], dot);
  }
  term -= logf(dot);
  if (c == KCH - 1) {
    float fz = 0.f;
#pragma unroll
    for (int t = 0; t < 7; ++t)
      fz = fmaf(recs[(size_t)t * NG + g], __expf(end_t[t]), fz);
    term -= logf(fz);                    // final logZ term (own vn)
    float mcf = 0.f;
    for (int cc = 0; cc < KCH; ++cc)
      mcf += recs[(size_t)15 * NG + (size_t)cc * BB + b];
    int se = (int)mcf - 1;
    int te = tags[(size_t)se * BB + b];
    term += end_t[te];                   // gold end transition
  }
  __shared__ float red[256];
  red[tid] = term;
  __syncthreads();
  for (int off = 128; off > 0; off >>= 1) {
    if (tid < off) red[tid] += red[tid + off];
    __syncthreads();
  }
  if (tid == 0) partials[blockIdx.x] = red[0];
}

// ---------------------------------------------------------------------------
// Kernel 3: deterministic tree-reduce of the block partials.
// ---------------------------------------------------------------------------
__global__ __launch_bounds__(1024)
void crf_reduce_kernel(const float* __restrict__ partials, int n,
                       float* __restrict__ out) {
  __shared__ float s[1024];
  int t = threadIdx.x;
  float v = 0.f;
  for (int i = t; i < n; i += 1024) v += partials[i];
  s[t] = v;
  __syncthreads();
  for (int off = 512; off > 0; off >>= 1) {
    if (t < off) s[t] += s[t + off];
    __syncthreads();
  }
  if (t == 0) out[0] = s[0];
}

extern "C" void kernel_launch(void* const* d_in, const int* in_sizes, int n_in,
                              void* d_out, int out_size, void* d_ws, size_t ws_size,
                              hipStream_t stream) {
  const float* em      = (const float*)d_in[0];
  const int*   tags    = (const int*)d_in[1];
  const int*   qmask   = (const int*)d_in[2];
  const int*   mask    = (const int*)d_in[3];
  const float* start_t = (const float*)d_in[4];
  const float* end_t   = (const float*)d_in[5];
  const float* self_t  = (const float*)d_in[6];
  const float* other_t = (const float*)d_in[7];

  float* recs = (float*)d_ws;

  constexpr int KCH = 64;     // CC=32; ws need ~8.9 MB
  constexpr int NG  = KCH * BB;
  float* partials = recs + (size_t)NFLD * NG;

  int fwd_blocks = NG / 256;          // 512 -> 2048 fwd waves
  int bwd_blocks = NG / 256;          // 512 -> 2048 bwd waves
  crf_chunk_kernel<KCH><<<fwd_blocks + bwd_blocks, 256, 0, stream>>>(
      em, tags, qmask, mask, self_t, other_t, recs);
  crf_junction_kernel<KCH><<<NG / 256, 256, 0, stream>>>(
      recs, em, tags, start_t, end_t, partials);
  crf_reduce_kernel<<<1, 1024, 0, stream>>>(partials, NG / 256, (float*)d_out);
}